// Round 8
// baseline (227.156 us; speedup 1.0000x reference)
//
#include <hip/hip_runtime.h>
#include <math.h>

static constexpr int CH_IN  = 128;
static constexpr int CH_HID = 128;
static constexpr int CH_OUT = 64;
static constexpr int NSH    = 8;     // histogram shards (~XCD count)

typedef __attribute__((ext_vector_type(8))) short bf16x8;
typedef __attribute__((ext_vector_type(4))) float f32x4;

// ---------- bf16 helpers (RNE pack, cheap unpack) ----------

__device__ __forceinline__ float bf2f(unsigned short u) {
    return __uint_as_float(((unsigned int)u) << 16);
}
__device__ __forceinline__ unsigned short f2bf(float f) {
    unsigned int u = __float_as_uint(f);
    u = (u + 0x7fffu + ((u >> 16) & 1u)) >> 16;   // round-to-nearest-even
    return (unsigned short)u;
}
__device__ __forceinline__ unsigned int pack2(float lo, float hi) {
    return (unsigned int)f2bf(lo) | ((unsigned int)f2bf(hi) << 16);
}
__device__ __forceinline__ void unpack2(unsigned int u, float& lo, float& hi) {
    lo = __uint_as_float(u << 16);
    hi = __uint_as_float(u & 0xffff0000u);
}
__device__ __forceinline__ unsigned int relu2(unsigned int u) {
    unsigned int m = 0;
    if (!(u & 0x8000u)) m |= 0xffffu;
    if (!(u & 0x80000000u)) m |= 0xffff0000u;
    return u & m;
}

// ---------- fused setup: zero shard counters + transpose/convert both weights ----------

__global__ void k_setup(int* __restrict__ cnt_s, int zn,
                        const float* __restrict__ W1, unsigned short* __restrict__ w1t,
                        const float* __restrict__ W2, unsigned short* __restrict__ w2t) {
    int i = blockIdx.x * blockDim.x + threadIdx.x;
    if (i < zn) { cnt_s[i] = 0; return; }
    int j = i - zn;
    if (j < CH_HID * 128) {
        int c = j >> 7, k = j & 127;
        w1t[(size_t)c * 128 + k] = f2bf(W1[(size_t)k * CH_HID + c]);
        return;
    }
    j -= CH_HID * 128;
    if (j < CH_OUT * 128) {
        int c = j >> 7, k = j & 127;
        w2t[(size_t)c * 128 + k] = f2bf(W2[(size_t)k * CH_OUT + c]);
    }
}

// ---------- CSR build: sharded histogram (single returning-atomic pass) ----------

__global__ void k_hist8(const int* __restrict__ ei, int* __restrict__ cnt_s,
                        int* __restrict__ eord, int E, int N) {
    int e = blockIdx.x * blockDim.x + threadIdx.x;
    if (e < E) {
        int sh = (e >> 8) & (NSH - 1);
        eord[e] = atomicAdd(&cnt_s[sh * N + ei[E + e]], 1);
    }
}

// per-node: exclusive prefix over shards (in place) + total -> cnt[d]
__global__ void k_shardscan(int* __restrict__ cnt_s, int* __restrict__ cnt, int N) {
    int d = blockIdx.x * blockDim.x + threadIdx.x;
    if (d >= N) return;
    int run = 0;
    #pragma unroll
    for (int s = 0; s < NSH; ++s) {
        int idx = s * N + d;
        int c = cnt_s[idx];
        cnt_s[idx] = run;
        run += c;
    }
    cnt[d] = run;
}

// ---------- 2-kernel exclusive scan: rowptr[i+1] = sum(cnt[0..i]) ----------

__device__ __forceinline__ int block_incl_scan_256(int v, int lane, int wid) {
    __shared__ int wtot[4];
    int s = v;
    #pragma unroll
    for (int off = 1; off < 64; off <<= 1) {
        int t = __shfl_up(s, off, 64);
        if (lane >= off) s += t;
    }
    if (lane == 63) wtot[wid] = s;
    __syncthreads();
    int woff = 0;
    for (int j = 0; j < wid; ++j) woff += wtot[j];
    return s + woff;
}

__global__ void k_scan_pre(const int* __restrict__ cnt, int* __restrict__ rowptr,
                           int* __restrict__ bsum, int N) {
    const int tid = threadIdx.x, lane = tid & 63, wid = tid >> 6;
    const int i = blockIdx.x * 256 + tid;
    int v = (i < N) ? cnt[i] : 0;
    int s = block_incl_scan_256(v, lane, wid);
    if (i < N) rowptr[i + 1] = s;
    if (tid == 255) bsum[blockIdx.x] = s;
}

// adds sum(bsum[0..bid-1]) to this block's 256 rowptr entries (nb <= 256)
__global__ void k_scan_add(int* __restrict__ rowptr, const int* __restrict__ bsum, int N) {
    __shared__ int wsum[4];
    __shared__ int off_s;
    const int tid = threadIdx.x, lane = tid & 63, wid = tid >> 6;
    const int bid = blockIdx.x;
    int v = (tid < bid) ? bsum[tid] : 0;
    #pragma unroll
    for (int off = 32; off > 0; off >>= 1) v += __shfl_xor(v, off, 64);
    if (lane == 0) wsum[wid] = v;
    __syncthreads();
    if (tid == 0) off_s = wsum[0] + wsum[1] + wsum[2] + wsum[3];
    __syncthreads();
    int i = bid * 256 + tid;
    if (i < N) {
        rowptr[i + 1] += off_s;
        if (i == 0) rowptr[0] = 0;
    }
}

// atomic-free fill: pos = rowptr[d] + shard-prefix + ordinal; epack = {src, bits(w)}
__global__ void k_fill(const int* __restrict__ ei, const float* __restrict__ w,
                       const int* __restrict__ eord, const int* __restrict__ rowptr,
                       const int* __restrict__ cnt_s, int2* __restrict__ epack, int E, int N) {
    int e = blockIdx.x * blockDim.x + threadIdx.x;
    if (e < E) {
        int d = ei[E + e];
        int sh = (e >> 8) & (NSH - 1);
        int pos = rowptr[d] + cnt_s[sh * N + d] + eord[e];
        epack[pos] = make_int2(ei[e], __float_as_int(w[e]));
    }
}

// dinv[n] = rsqrt(1 + sum of row weights)  (self-loop weight 1 included)
__global__ void k_degdinv(const int* __restrict__ rowptr, const int2* __restrict__ epack,
                          float* __restrict__ dinv, int N) {
    int n = blockIdx.x * blockDim.x + threadIdx.x;
    if (n >= N) return;
    int beg = rowptr[n], end = rowptr[n + 1];
    float s = 1.0f;
    for (int i = beg; i < end; ++i) s += __int_as_float(epack[i].y);
    dinv[n] = rsqrtf(s);
}

// epack.y: w -> nm = w * dinv[src]  (removes per-edge dinv gather from agg passes)
__global__ void k_nm(int2* __restrict__ epack, const float* __restrict__ dinv, int Etot) {
    int e = blockIdx.x * blockDim.x + threadIdx.x;
    if (e < Etot) {
        int2 p = epack[e];
        epack[e] = make_int2(p.x, __float_as_int(__int_as_float(p.y) * dinv[p.x]));
    }
}

// ---------- MFMA GEMM: 64 rows/block (4 waves x 16), K=128, bf16 in/out ----------

template<int COLS, bool RELU_IN, typename TIN>
__global__ void k_gemm_mfma(const TIN* __restrict__ X, const unsigned short* __restrict__ Wt,
                            unsigned short* __restrict__ H, int N) {
    constexpr int NCT = COLS / 16;
    __shared__ unsigned short As[64 * 136];
    const int tid = threadIdx.x;
    const int lane = tid & 63, wv = tid >> 6;
    const int row0 = blockIdx.x * 64;

    if constexpr (sizeof(TIN) == 4) {
        #pragma unroll
        for (int j = 0; j < 8; ++j) {
            int f = j * 256 + tid;
            int row = f >> 5, col = (f & 31) * 4;
            float4 v = make_float4(0.f, 0.f, 0.f, 0.f);
            if (row0 + row < N)
                v = *reinterpret_cast<const float4*>((const float*)X + (size_t)(row0 + row) * CH_IN + col);
            uint2 p;
            p.x = pack2(v.x, v.y);
            p.y = pack2(v.z, v.w);
            *reinterpret_cast<uint2*>(&As[row * 136 + col]) = p;
        }
    } else {
        #pragma unroll
        for (int j = 0; j < 4; ++j) {
            int f = j * 256 + tid;
            int row = f >> 4, col = (f & 15) * 8;
            uint4 v = make_uint4(0u, 0u, 0u, 0u);
            if (row0 + row < N) {
                v = *reinterpret_cast<const uint4*>((const unsigned short*)X + (size_t)(row0 + row) * CH_IN + col);
                if (RELU_IN) {
                    v.x = relu2(v.x); v.y = relu2(v.y);
                    v.z = relu2(v.z); v.w = relu2(v.w);
                }
            }
            *reinterpret_cast<uint4*>(&As[row * 136 + col]) = v;
        }
    }
    __syncthreads();

    const int rw0  = wv * 16;
    const int arow = rw0 + (lane & 15);
    const int kgrp = (lane >> 4) * 8;
    f32x4 acc[NCT];
    #pragma unroll
    for (int c = 0; c < NCT; ++c) acc[c] = f32x4{0.f, 0.f, 0.f, 0.f};

    #pragma unroll
    for (int kk = 0; kk < 4; ++kk) {
        bf16x8 af = *reinterpret_cast<const bf16x8*>(&As[arow * 136 + kk * 32 + kgrp]);
        #pragma unroll
        for (int ct = 0; ct < NCT; ++ct) {
            bf16x8 bf = *reinterpret_cast<const bf16x8*>(
                Wt + (size_t)(ct * 16 + (lane & 15)) * 128 + kk * 32 + kgrp);
            acc[ct] = __builtin_amdgcn_mfma_f32_16x16x32_bf16(af, bf, acc[ct], 0, 0, 0);
        }
    }

    const int orow0 = row0 + rw0 + (lane >> 4) * 4;
    const int ocol  = lane & 15;
    #pragma unroll
    for (int ct = 0; ct < NCT; ++ct) {
        #pragma unroll
        for (int r = 0; r < 4; ++r) {
            int row = orow0 + r;
            if (row < N) H[(size_t)row * COLS + ct * 16 + ocol] = f2bf(acc[ct][r]);
        }
    }
}

// ---------- strip aggregation (layer 1): 4 strips x 32 channels, L2-resident ----------
// Grid: [4 strips][nodes/4]; 256 thr = 4 waves, wave = 1 node.
// lane: ch = lane&31 (within strip), sub = lane>>5 (edge parity) -> 2 edges/instr.
// out1[n][32q+ch] = b + h[n][.]*dd^2 + dd * sum_e h[src_e][.] * nm_e

__global__ void k_agg128s(const int* __restrict__ rowptr, const int2* __restrict__ epack,
                          const float* __restrict__ dinv, const unsigned short* __restrict__ h,
                          const float* __restrict__ b, unsigned short* __restrict__ out,
                          int N, int nbs) {
    const int q    = blockIdx.x / nbs;            // strip 0..3
    const int nb   = blockIdx.x - q * nbs;
    const int node = nb * 4 + (threadIdx.x >> 6);
    const int lane = threadIdx.x & 63;
    if (node >= N) return;
    const int ch  = lane & 31, sub = lane >> 5;
    const int c0  = q * 32;
    const int beg = rowptr[node], end = rowptr[node + 1];
    const float dd = dinv[node];

    float a[8];
    #pragma unroll
    for (int k = 0; k < 8; ++k) a[k] = 0.f;

    for (int i0 = beg; i0 < end; i0 += 64) {
        const int m = min(64, end - i0);
        int s_l = 0; float nm_l = 0.f;
        if (lane < m) {
            int2 p = epack[i0 + lane];
            s_l = p.x;
            nm_l = __int_as_float(p.y);           // nm precomputed = w * dinv[src]
        }
        for (int j = 0; j < m; j += 16) {
            #pragma unroll
            for (int k = 0; k < 8; ++k) {
                int idx = j + 2 * k + sub;        // <= 63; idx >= m has nm = 0
                int   s  = __shfl(s_l, idx, 64);
                float nm = __shfl(nm_l, idx, 64);
                a[k] = fmaf(bf2f(h[(size_t)s * 128 + c0 + ch]), nm, a[k]);
            }
        }
    }
    float v = ((a[0] + a[1]) + (a[2] + a[3])) + ((a[4] + a[5]) + (a[6] + a[7]));
    v += __shfl_xor(v, 32, 64);                   // combine edge parities (same ch)
    float hn = bf2f(h[(size_t)node * 128 + c0 + ch]);
    v = fmaf(v, dd, fmaf(hn, dd * dd, b[c0 + ch]));
    if (sub == 0) out[(size_t)node * 128 + c0 + ch] = f2bf(v);
}

// ---------- layer-2 aggregation + fused log_softmax: wave per node ----------

__global__ void k_agg64(const int* __restrict__ rowptr, const int2* __restrict__ epack,
                        const float* __restrict__ dinv, const unsigned short* __restrict__ h,
                        const float* __restrict__ b, float* __restrict__ out, int N) {
    const int node = (blockIdx.x * blockDim.x + threadIdx.x) >> 6;
    const int lane = threadIdx.x & 63;
    if (node >= N) return;
    const int beg = rowptr[node], end = rowptr[node + 1];
    const float dd = dinv[node];

    float a[8];
    #pragma unroll
    for (int k = 0; k < 8; ++k) a[k] = 0.f;

    for (int i0 = beg; i0 < end; i0 += 64) {
        const int m = min(64, end - i0);
        int s_l = 0; float nm_l = 0.f;
        if (lane < m) {
            int2 p = epack[i0 + lane];
            s_l = p.x;
            nm_l = __int_as_float(p.y);           // nm precomputed
        }
        int j = 0;
        for (; j + 8 <= m; j += 8) {
            #pragma unroll
            for (int k = 0; k < 8; ++k) {
                int   s  = __shfl(s_l, j + k, 64);
                float nm = __shfl(nm_l, j + k, 64);
                a[k] = fmaf(bf2f(h[(size_t)s * 64 + lane]), nm, a[k]);
            }
        }
        for (; j + 4 <= m; j += 4) {
            #pragma unroll
            for (int k = 0; k < 4; ++k) {
                int   s  = __shfl(s_l, j + k, 64);
                float nm = __shfl(nm_l, j + k, 64);
                a[k] = fmaf(bf2f(h[(size_t)s * 64 + lane]), nm, a[k]);
            }
        }
        for (; j < m; ++j) {
            int   s  = __shfl(s_l, j, 64);
            float nm = __shfl(nm_l, j, 64);
            a[0] = fmaf(bf2f(h[(size_t)s * 64 + lane]), nm, a[0]);
        }
    }
    float v = ((a[0] + a[1]) + (a[2] + a[3])) + ((a[4] + a[5]) + (a[6] + a[7]));
    v = fmaf(v, dd, fmaf(bf2f(h[(size_t)node * 64 + lane]), dd * dd, b[lane]));

    float mx = v;
    #pragma unroll
    for (int off = 32; off > 0; off >>= 1) mx = fmaxf(mx, __shfl_xor(mx, off, 64));
    float ex = expf(v - mx);
    float sm = ex;
    #pragma unroll
    for (int off = 32; off > 0; off >>= 1) sm += __shfl_xor(sm, off, 64);
    out[(size_t)node * 64 + lane] = (v - mx) - logf(sm);
}

extern "C" void kernel_launch(void* const* d_in, const int* in_sizes, int n_in,
                              void* d_out, int out_size, void* d_ws, size_t ws_size,
                              hipStream_t stream) {
    const float* x  = (const float*)d_in[0];
    const int*   ei = (const int*)d_in[1];     // [2,E]: src = ei[e], dst = ei[E+e]
    const float* w  = (const float*)d_in[2];
    const float* W1 = (const float*)d_in[3];
    const float* b1 = (const float*)d_in[4];
    const float* W2 = (const float*)d_in[5];
    const float* b2 = (const float*)d_in[6];
    float* out = (float*)d_out;

    const int N = in_sizes[0] / CH_IN;
    const int E = in_sizes[2];
    const int NB = (N + 255) / 256;            // scan blocks (<= 256)

    // workspace carve (float units; epack 8B-aligned, bf16 arrays 16B-aligned)
    float* ws0   = (float*)d_ws;
    float* ws    = ws0;
    float* dinv  = ws;               ws += N;
    int*   rowptr= (int*)ws;         ws += (N + 2);
    int*   cnt   = (int*)ws;         ws += N;
    int*   bsum  = (int*)ws;         ws += 256;
    int*   cnt_s = (int*)ws;         ws += (size_t)NSH * N;
    int*   eord  = (int*)ws;         ws += E;
    int2*  epack = (int2*)ws;        ws += (size_t)2 * E;
    { size_t off = (size_t)(ws - ws0) & 3; if (off) ws += 4 - off; }
    unsigned short* w1t  = (unsigned short*)ws;  ws += (size_t)CH_HID * 128 / 2;
    unsigned short* w2t  = (unsigned short*)ws;  ws += (size_t)CH_OUT * 128 / 2;
    unsigned short* h1   = (unsigned short*)ws;  ws += (size_t)N * CH_HID / 2;
    unsigned short* out1 = (unsigned short*)ws;  ws += (size_t)N * CH_HID / 2;
    unsigned short* h2   = (unsigned short*)ws;  ws += (size_t)N * CH_OUT / 2;

    const int B = 256;
    const int setup_total = NSH * N + CH_HID * 128 + CH_OUT * 128;

    // 0) fused setup: zero shard counters + both weight transposes
    k_setup<<<(setup_total + B - 1) / B, B, 0, stream>>>(cnt_s, NSH * N, W1, w1t, W2, w2t);

    // 1) sharded histogram with ordinal capture (only atomic pass)
    k_hist8<<<(E + B - 1) / B, B, 0, stream>>>(ei, cnt_s, eord, E, N);
    k_shardscan<<<(N + B - 1) / B, B, 0, stream>>>(cnt_s, cnt, N);

    // 2) rowptr = exclusive scan(cnt); atomic-free fill; degree; nm precompute
    k_scan_pre<<<NB, 256, 0, stream>>>(cnt, rowptr, bsum, N);
    k_scan_add<<<NB, 256, 0, stream>>>(rowptr, bsum, N);
    k_fill<<<(E + B - 1) / B, B, 0, stream>>>(ei, w, eord, rowptr, cnt_s, epack, E, N);
    k_degdinv<<<(N + B - 1) / B, B, 0, stream>>>(rowptr, epack, dinv, N);
    k_nm<<<(E + B - 1) / B, B, 0, stream>>>(epack, dinv, E);

    // 3) h1 = x @ W1  (fp32 in -> bf16 LDS -> MFMA -> bf16 out)
    k_gemm_mfma<CH_HID, false, float><<<(N + 63) / 64, 256, 0, stream>>>(x, w1t, h1, N);

    // 4) out1 = agg(h1) in 4 L2-resident strips of 32 channels (single launch)
    {
        const int nbs = (N + 3) / 4;           // node-blocks per strip
        k_agg128s<<<4 * nbs, 256, 0, stream>>>(rowptr, epack, dinv, h1, b1, out1, N, nbs);
    }

    // 5) h2 = relu(out1) @ W2  (bf16 in w/ fused relu, MFMA, bf16 out)
    k_gemm_mfma<CH_OUT, true, unsigned short><<<(N + 63) / 64, 256, 0, stream>>>(out1, w2t, h2, N);

    // 6) out = log_softmax(b2 + self + aggregate), fused, fp32 into d_out
    k_agg64<<<(N * 64 + B - 1) / B, B, 0, stream>>>(rowptr, epack, dinv, h2, b2, out, N);
}

// Round 9
// 175.774 us; speedup vs baseline: 1.2923x; 1.2923x over previous
//
#include <hip/hip_runtime.h>
#include <math.h>

static constexpr int CH_IN  = 128;
static constexpr int CH_HID = 128;
static constexpr int CH_OUT = 64;
static constexpr int NSH    = 8;     // histogram shards (~XCD count)

typedef __attribute__((ext_vector_type(8))) short bf16x8;
typedef __attribute__((ext_vector_type(4))) float f32x4;

// ---------- bf16 helpers (RNE pack, cheap unpack) ----------

__device__ __forceinline__ float bf2f(unsigned short u) {
    return __uint_as_float(((unsigned int)u) << 16);
}
__device__ __forceinline__ unsigned short f2bf(float f) {
    unsigned int u = __float_as_uint(f);
    u = (u + 0x7fffu + ((u >> 16) & 1u)) >> 16;   // round-to-nearest-even
    return (unsigned short)u;
}
__device__ __forceinline__ unsigned int pack2(float lo, float hi) {
    return (unsigned int)f2bf(lo) | ((unsigned int)f2bf(hi) << 16);
}
__device__ __forceinline__ void unpack2(unsigned int u, float& lo, float& hi) {
    lo = __uint_as_float(u << 16);
    hi = __uint_as_float(u & 0xffff0000u);
}
__device__ __forceinline__ unsigned int relu2(unsigned int u) {
    unsigned int m = 0;
    if (!(u & 0x8000u)) m |= 0xffffu;
    if (!(u & 0x80000000u)) m |= 0xffff0000u;
    return u & m;
}

// ---------- fused setup: zero shard counters + transpose/convert both weights ----------

__global__ void k_setup(int* __restrict__ cnt_s, int zn,
                        const float* __restrict__ W1, unsigned short* __restrict__ w1t,
                        const float* __restrict__ W2, unsigned short* __restrict__ w2t) {
    int i = blockIdx.x * blockDim.x + threadIdx.x;
    if (i < zn) { cnt_s[i] = 0; return; }
    int j = i - zn;
    if (j < CH_HID * 128) {
        int c = j >> 7, k = j & 127;
        w1t[(size_t)c * 128 + k] = f2bf(W1[(size_t)k * CH_HID + c]);
        return;
    }
    j -= CH_HID * 128;
    if (j < CH_OUT * 128) {
        int c = j >> 7, k = j & 127;
        w2t[(size_t)c * 128 + k] = f2bf(W2[(size_t)k * CH_OUT + c]);
    }
}

// ---------- CSR build: sharded histogram (single returning-atomic pass) ----------

__global__ void k_hist8(const int* __restrict__ ei, int* __restrict__ cnt_s,
                        int* __restrict__ eord, int E, int N) {
    int e = blockIdx.x * blockDim.x + threadIdx.x;
    if (e < E) {
        int sh = (e >> 8) & (NSH - 1);
        eord[e] = atomicAdd(&cnt_s[sh * N + ei[E + e]], 1);
    }
}

// ---------- merged: per-node shard prefix + block-level inclusive scan ----------
// cnt_s[s][d] -> exclusive shard prefix (in place); node total feeds block scan
// writing rowptr[d+1] (block-local) and bsum[blockIdx].

__global__ void k_shardscan_pre(int* __restrict__ cnt_s, int* __restrict__ rowptr,
                                int* __restrict__ bsum, int N) {
    __shared__ int wtot[4];
    const int tid = threadIdx.x, lane = tid & 63, wid = tid >> 6;
    const int d = blockIdx.x * 256 + tid;
    int run = 0;
    if (d < N) {
        #pragma unroll
        for (int s = 0; s < NSH; ++s) {
            int idx = s * N + d;
            int c = cnt_s[idx];
            cnt_s[idx] = run;
            run += c;
        }
    }
    // block inclusive scan of run
    int s = run;
    #pragma unroll
    for (int off = 1; off < 64; off <<= 1) {
        int t = __shfl_up(s, off, 64);
        if (lane >= off) s += t;
    }
    if (lane == 63) wtot[wid] = s;
    __syncthreads();
    int woff = 0;
    for (int j = 0; j < wid; ++j) woff += wtot[j];
    s += woff;
    if (d < N) rowptr[d + 1] = s;
    if (tid == 255) bsum[blockIdx.x] = s;
}

// adds sum(bsum[0..bid-1]) to this block's 256 rowptr entries (nb <= 256)
__global__ void k_scan_add(int* __restrict__ rowptr, const int* __restrict__ bsum, int N) {
    __shared__ int wsum[4];
    __shared__ int off_s;
    const int tid = threadIdx.x, lane = tid & 63, wid = tid >> 6;
    const int bid = blockIdx.x;
    int v = (tid < bid) ? bsum[tid] : 0;
    #pragma unroll
    for (int off = 32; off > 0; off >>= 1) v += __shfl_xor(v, off, 64);
    if (lane == 0) wsum[wid] = v;
    __syncthreads();
    if (tid == 0) off_s = wsum[0] + wsum[1] + wsum[2] + wsum[3];
    __syncthreads();
    int i = bid * 256 + tid;
    if (i < N) {
        rowptr[i + 1] += off_s;
        if (i == 0) rowptr[0] = 0;
    }
}

// atomic-free fill: pos = rowptr[d] + shard-prefix + ordinal; epack = {src, bits(w)}
__global__ void k_fill(const int* __restrict__ ei, const float* __restrict__ w,
                       const int* __restrict__ eord, const int* __restrict__ rowptr,
                       const int* __restrict__ cnt_s, int2* __restrict__ epack, int E, int N) {
    int e = blockIdx.x * blockDim.x + threadIdx.x;
    if (e < E) {
        int d = ei[E + e];
        int sh = (e >> 8) & (NSH - 1);
        int pos = rowptr[d] + cnt_s[sh * N + d] + eord[e];
        epack[pos] = make_int2(ei[e], __float_as_int(w[e]));
    }
}

// dinv[n] = rsqrt(1 + sum of row weights); wave per node, coalesced
__global__ void k_degdinv(const int* __restrict__ rowptr, const int2* __restrict__ epack,
                          float* __restrict__ dinv, int N) {
    const int node = (blockIdx.x * blockDim.x + threadIdx.x) >> 6;
    const int lane = threadIdx.x & 63;
    if (node >= N) return;
    const int beg = rowptr[node], end = rowptr[node + 1];
    float s = 0.f;
    for (int i = beg + lane; i < end; i += 64) s += __int_as_float(epack[i].y);
    #pragma unroll
    for (int off = 32; off > 0; off >>= 1) s += __shfl_xor(s, off, 64);
    if (lane == 0) dinv[node] = rsqrtf(1.0f + s);
}

// ---------- MFMA GEMM: 64 rows/block (4 waves x 16), K=128, bf16 in/out ----------

template<int COLS, bool RELU_IN, typename TIN>
__global__ void k_gemm_mfma(const TIN* __restrict__ X, const unsigned short* __restrict__ Wt,
                            unsigned short* __restrict__ H, int N) {
    constexpr int NCT = COLS / 16;
    __shared__ unsigned short As[64 * 136];
    const int tid = threadIdx.x;
    const int lane = tid & 63, wv = tid >> 6;
    const int row0 = blockIdx.x * 64;

    if constexpr (sizeof(TIN) == 4) {
        #pragma unroll
        for (int j = 0; j < 8; ++j) {
            int f = j * 256 + tid;
            int row = f >> 5, col = (f & 31) * 4;
            float4 v = make_float4(0.f, 0.f, 0.f, 0.f);
            if (row0 + row < N)
                v = *reinterpret_cast<const float4*>((const float*)X + (size_t)(row0 + row) * CH_IN + col);
            uint2 p;
            p.x = pack2(v.x, v.y);
            p.y = pack2(v.z, v.w);
            *reinterpret_cast<uint2*>(&As[row * 136 + col]) = p;
        }
    } else {
        #pragma unroll
        for (int j = 0; j < 4; ++j) {
            int f = j * 256 + tid;
            int row = f >> 4, col = (f & 15) * 8;
            uint4 v = make_uint4(0u, 0u, 0u, 0u);
            if (row0 + row < N) {
                v = *reinterpret_cast<const uint4*>((const unsigned short*)X + (size_t)(row0 + row) * CH_IN + col);
                if (RELU_IN) {
                    v.x = relu2(v.x); v.y = relu2(v.y);
                    v.z = relu2(v.z); v.w = relu2(v.w);
                }
            }
            *reinterpret_cast<uint4*>(&As[row * 136 + col]) = v;
        }
    }
    __syncthreads();

    const int rw0  = wv * 16;
    const int arow = rw0 + (lane & 15);
    const int kgrp = (lane >> 4) * 8;
    f32x4 acc[NCT];
    #pragma unroll
    for (int c = 0; c < NCT; ++c) acc[c] = f32x4{0.f, 0.f, 0.f, 0.f};

    #pragma unroll
    for (int kk = 0; kk < 4; ++kk) {
        bf16x8 af = *reinterpret_cast<const bf16x8*>(&As[arow * 136 + kk * 32 + kgrp]);
        #pragma unroll
        for (int ct = 0; ct < NCT; ++ct) {
            bf16x8 bf = *reinterpret_cast<const bf16x8*>(
                Wt + (size_t)(ct * 16 + (lane & 15)) * 128 + kk * 32 + kgrp);
            acc[ct] = __builtin_amdgcn_mfma_f32_16x16x32_bf16(af, bf, acc[ct], 0, 0, 0);
        }
    }

    const int orow0 = row0 + rw0 + (lane >> 4) * 4;
    const int ocol  = lane & 15;
    #pragma unroll
    for (int ct = 0; ct < NCT; ++ct) {
        #pragma unroll
        for (int r = 0; r < 4; ++r) {
            int row = orow0 + r;
            if (row < N) H[(size_t)row * COLS + ct * 16 + ocol] = f2bf(acc[ct][r]);
        }
    }
}

// ---------- CSR aggregation: wave per node, padded ILP8 (no serial tails) ----------
// out[n][:] = b + h[n]*dd^2 + dd * sum_e h[src_e] * (w_e * dinv[src_e])
// Lanes >= m carry s=0/nm=0: padded gathers hit row 0 (hot), contribute 0.

__global__ void k_agg128(const int* __restrict__ rowptr, const int2* __restrict__ epack,
                         const float* __restrict__ dinv, const unsigned short* __restrict__ h,
                         const float* __restrict__ b, unsigned short* __restrict__ out, int N) {
    const int node = (blockIdx.x * blockDim.x + threadIdx.x) >> 6;
    const int lane = threadIdx.x & 63;
    if (node >= N) return;
    const int beg = rowptr[node], end = rowptr[node + 1];
    const float dd = dinv[node];
    const unsigned int* hp = (const unsigned int*)h;   // 64 uints per row

    float2 a[8];
    #pragma unroll
    for (int k = 0; k < 8; ++k) a[k] = make_float2(0.f, 0.f);

    for (int i0 = beg; i0 < end; i0 += 64) {
        const int m = min(64, end - i0);
        int s_l = 0; float nm_l = 0.f;
        if (lane < m) {
            int2 p = epack[i0 + lane];
            s_l = p.x;
            nm_l = __int_as_float(p.y) * dinv[p.x];    // dinv: 200 KB, L2-hit
        }
        for (int j = 0; j < m; j += 8) {
            #pragma unroll
            for (int k = 0; k < 8; ++k) {
                int   s  = __shfl(s_l, j + k, 64);     // j+k may be >= m -> s=0, nm=0
                float nm = __shfl(nm_l, j + k, 64);
                float lo, hi; unpack2(hp[(size_t)s * 64 + lane], lo, hi);
                a[k].x = fmaf(lo, nm, a[k].x);
                a[k].y = fmaf(hi, nm, a[k].y);
            }
        }
    }
    float sx = ((a[0].x + a[1].x) + (a[2].x + a[3].x)) + ((a[4].x + a[5].x) + (a[6].x + a[7].x));
    float sy = ((a[0].y + a[1].y) + (a[2].y + a[3].y)) + ((a[4].y + a[5].y) + (a[6].y + a[7].y));
    float hnl, hnh; unpack2(hp[(size_t)node * 64 + lane], hnl, hnh);
    float2 bv = ((const float2*)b)[lane];
    sx = fmaf(sx, dd, fmaf(hnl, dd * dd, bv.x));
    sy = fmaf(sy, dd, fmaf(hnh, dd * dd, bv.y));
    ((unsigned int*)out)[(size_t)node * 64 + lane] = pack2(sx, sy);
}

// layer-2 aggregation + fused log_softmax; fp32 out (d_out)
__global__ void k_agg64(const int* __restrict__ rowptr, const int2* __restrict__ epack,
                        const float* __restrict__ dinv, const unsigned short* __restrict__ h,
                        const float* __restrict__ b, float* __restrict__ out, int N) {
    const int node = (blockIdx.x * blockDim.x + threadIdx.x) >> 6;
    const int lane = threadIdx.x & 63;
    if (node >= N) return;
    const int beg = rowptr[node], end = rowptr[node + 1];
    const float dd = dinv[node];

    float a[8];
    #pragma unroll
    for (int k = 0; k < 8; ++k) a[k] = 0.f;

    for (int i0 = beg; i0 < end; i0 += 64) {
        const int m = min(64, end - i0);
        int s_l = 0; float nm_l = 0.f;
        if (lane < m) {
            int2 p = epack[i0 + lane];
            s_l = p.x;
            nm_l = __int_as_float(p.y) * dinv[p.x];
        }
        for (int j = 0; j < m; j += 8) {
            #pragma unroll
            for (int k = 0; k < 8; ++k) {
                int   s  = __shfl(s_l, j + k, 64);
                float nm = __shfl(nm_l, j + k, 64);
                a[k] = fmaf(bf2f(h[(size_t)s * 64 + lane]), nm, a[k]);
            }
        }
    }
    float v = ((a[0] + a[1]) + (a[2] + a[3])) + ((a[4] + a[5]) + (a[6] + a[7]));
    v = fmaf(v, dd, fmaf(bf2f(h[(size_t)node * 64 + lane]), dd * dd, b[lane]));

    float mx = v;
    #pragma unroll
    for (int off = 32; off > 0; off >>= 1) mx = fmaxf(mx, __shfl_xor(mx, off, 64));
    float ex = expf(v - mx);
    float sm = ex;
    #pragma unroll
    for (int off = 32; off > 0; off >>= 1) sm += __shfl_xor(sm, off, 64);
    out[(size_t)node * 64 + lane] = (v - mx) - logf(sm);
}

extern "C" void kernel_launch(void* const* d_in, const int* in_sizes, int n_in,
                              void* d_out, int out_size, void* d_ws, size_t ws_size,
                              hipStream_t stream) {
    const float* x  = (const float*)d_in[0];
    const int*   ei = (const int*)d_in[1];     // [2,E]: src = ei[e], dst = ei[E+e]
    const float* w  = (const float*)d_in[2];
    const float* W1 = (const float*)d_in[3];
    const float* b1 = (const float*)d_in[4];
    const float* W2 = (const float*)d_in[5];
    const float* b2 = (const float*)d_in[6];
    float* out = (float*)d_out;

    const int N = in_sizes[0] / CH_IN;
    const int E = in_sizes[2];
    const int NB = (N + 255) / 256;            // scan blocks (<= 256)

    // workspace carve (float units; epack 8B-aligned, bf16 arrays 16B-aligned)
    float* ws0   = (float*)d_ws;
    float* ws    = ws0;
    float* dinv  = ws;               ws += N;
    int*   rowptr= (int*)ws;         ws += (N + 2);
    int*   bsum  = (int*)ws;         ws += 256;
    int*   cnt_s = (int*)ws;         ws += (size_t)NSH * N;
    int*   eord  = (int*)ws;         ws += E;
    int2*  epack = (int2*)ws;        ws += (size_t)2 * E;
    { size_t off = (size_t)(ws - ws0) & 3; if (off) ws += 4 - off; }
    unsigned short* w1t  = (unsigned short*)ws;  ws += (size_t)CH_HID * 128 / 2;
    unsigned short* w2t  = (unsigned short*)ws;  ws += (size_t)CH_OUT * 128 / 2;
    unsigned short* h1   = (unsigned short*)ws;  ws += (size_t)N * CH_HID / 2;
    unsigned short* out1 = (unsigned short*)ws;  ws += (size_t)N * CH_HID / 2;
    unsigned short* h2   = (unsigned short*)ws;  ws += (size_t)N * CH_OUT / 2;

    const int B = 256;
    const int setup_total = NSH * N + CH_HID * 128 + CH_OUT * 128;

    // 0) fused setup: zero shard counters + both weight transposes
    k_setup<<<(setup_total + B - 1) / B, B, 0, stream>>>(cnt_s, NSH * N, W1, w1t, W2, w2t);

    // 1) sharded histogram with ordinal capture (only atomic pass)
    k_hist8<<<(E + B - 1) / B, B, 0, stream>>>(ei, cnt_s, eord, E, N);

    // 2) shard prefix + block scan; cross-block add; atomic-free fill; degree
    k_shardscan_pre<<<NB, 256, 0, stream>>>(cnt_s, rowptr, bsum, N);
    k_scan_add<<<NB, 256, 0, stream>>>(rowptr, bsum, N);
    k_fill<<<(E + B - 1) / B, B, 0, stream>>>(ei, w, eord, rowptr, cnt_s, epack, E, N);
    k_degdinv<<<(N * 64 + B - 1) / B, B, 0, stream>>>(rowptr, epack, dinv, N);

    // 3) h1 = x @ W1  (fp32 in -> bf16 LDS -> MFMA -> bf16 out)
    k_gemm_mfma<CH_HID, false, float><<<(N + 63) / 64, 256, 0, stream>>>(x, w1t, h1, N);

    // 4) out1 = b1 + self + neighbor aggregate (full-row bf16 gathers)
    k_agg128<<<(N * 64 + B - 1) / B, B, 0, stream>>>(rowptr, epack, dinv, h1, b1, out1, N);

    // 5) h2 = relu(out1) @ W2  (bf16 in w/ fused relu, MFMA, bf16 out)
    k_gemm_mfma<CH_OUT, true, unsigned short><<<(N + 63) / 64, 256, 0, stream>>>(out1, w2t, h2, N);

    // 6) out = log_softmax(b2 + self + aggregate), fused, fp32 into d_out
    k_agg64<<<(N * 64 + B - 1) / B, B, 0, stream>>>(rowptr, epack, dinv, h2, b2, out, N);
}